// Round 1
// baseline (999.283 us; speedup 1.0000x reference)
//
#include <hip/hip_runtime.h>

// ReaxFF bond energy + segment_sum into atoms.
// N_BONDS = 16777216, N_ATOMS = 1048576, N_TYPES = 16.

__global__ __launch_bounds__(256) void zero_out_kernel(float4* __restrict__ out, int n4) {
    int i = blockIdx.x * blockDim.x + threadIdx.x;
    if (i < n4) {
        out[i] = make_float4(0.f, 0.f, 0.f, 0.f);
    }
}

__device__ __forceinline__ float bond_e(int t, float bs, float bp, float bpp,
                                        const float* __restrict__ sp) {
    const float* p = sp + t * 5;
    float de_s = p[0], de_p = p[1], de_pp = p[2], p_be1 = p[3], p_be2 = p[4];
    // bs in (0.05, 1.0) -> strictly positive, fast pow/exp are safe.
    float pw = __powf(bs, p_be2);
    float e  = -de_s * bs * __expf(p_be1 * (1.0f - pw)) - de_p * bp - de_pp * bpp;
    return e;
}

__global__ __launch_bounds__(256) void bond_energy_kernel(
        const int4*   __restrict__ bond_type,
        const int4*   __restrict__ atom_i,
        const float4* __restrict__ bo_sigma,
        const float4* __restrict__ bo_pi,
        const float4* __restrict__ bo_pipi,
        const float*  __restrict__ bond_params,   // 16 x 5
        float*        __restrict__ e_atom,
        int n4) {
    __shared__ float sp[80];
    if (threadIdx.x < 80) sp[threadIdx.x] = bond_params[threadIdx.x];
    __syncthreads();

    int i = blockIdx.x * blockDim.x + threadIdx.x;
    if (i >= n4) return;

    int4   t   = bond_type[i];
    int4   a   = atom_i[i];
    float4 bs  = bo_sigma[i];
    float4 bp  = bo_pi[i];
    float4 bpp = bo_pipi[i];

    float e0 = bond_e(t.x, bs.x, bp.x, bpp.x, sp);
    float e1 = bond_e(t.y, bs.y, bp.y, bpp.y, sp);
    float e2 = bond_e(t.z, bs.z, bp.z, bpp.z, sp);
    float e3 = bond_e(t.w, bs.w, bp.w, bpp.w, sp);

#if defined(__AMDGCN__) || defined(__HIP_DEVICE_COMPILE__)
    unsafeAtomicAdd(&e_atom[a.x], e0);
    unsafeAtomicAdd(&e_atom[a.y], e1);
    unsafeAtomicAdd(&e_atom[a.z], e2);
    unsafeAtomicAdd(&e_atom[a.w], e3);
#else
    atomicAdd(&e_atom[a.x], e0);
    atomicAdd(&e_atom[a.y], e1);
    atomicAdd(&e_atom[a.z], e2);
    atomicAdd(&e_atom[a.w], e3);
#endif
}

extern "C" void kernel_launch(void* const* d_in, const int* in_sizes, int n_in,
                              void* d_out, int out_size, void* d_ws, size_t ws_size,
                              hipStream_t stream) {
    const int*   bond_type   = (const int*)  d_in[0];
    const int*   atom_i      = (const int*)  d_in[1];
    const float* bo_sigma    = (const float*)d_in[2];
    const float* bo_pi       = (const float*)d_in[3];
    const float* bo_pipi     = (const float*)d_in[4];
    const float* bond_params = (const float*)d_in[5];
    float*       e_atom      = (float*)d_out;

    int n_bonds = in_sizes[0];          // 16777216
    int n_atoms = out_size;             // 1048576

    // 1) zero the output (harness poisons it before every timed call)
    int n_out4 = n_atoms / 4;
    int zb = 256;
    int zg = (n_out4 + zb - 1) / zb;
    zero_out_kernel<<<zg, zb, 0, stream>>>((float4*)e_atom, n_out4);

    // 2) bond energy + scatter-add
    int n4 = n_bonds / 4;               // N_BONDS divisible by 4
    int tb = 256;
    int tg = (n4 + tb - 1) / tb;
    bond_energy_kernel<<<tg, tb, 0, stream>>>(
        (const int4*)bond_type, (const int4*)atom_i,
        (const float4*)bo_sigma, (const float4*)bo_pi, (const float4*)bo_pipi,
        bond_params, e_atom, n4);
}